// Round 3
// baseline (585.708 us; speedup 1.0000x reference)
//
#include <hip/hip_runtime.h>
#include <hip/hip_bf16.h>
#include <math.h>

#define T_SEQ 2048
#define HID   4096
#define NH    32
#define NKV   8
#define HD    128
#define QKVD  6144
#define KOFF  4096
#define VOFF  5120

typedef unsigned short u16;
typedef unsigned int   u32;
typedef __attribute__((ext_vector_type(4))) float f32x4;
typedef __attribute__((ext_vector_type(8))) short s16x8;
typedef __attribute__((ext_vector_type(4))) unsigned short u16x4;

__device__ inline u16 f2bf(float f) {
  u32 u = __float_as_uint(f);
  u32 r = u + 0x7FFFu + ((u >> 16) & 1u);
  return (u16)(r >> 16);
}
__device__ inline float bf2f(u16 h) { return __uint_as_float(((u32)h) << 16); }

__device__ inline void gl_lds16(const void* g, void* l) {
  __builtin_amdgcn_global_load_lds((const __attribute__((address_space(1))) void*)g,
                                   (__attribute__((address_space(3))) void*)l, 16, 0, 0);
}

// ---------------- cast fp32 -> bf16 (vectorized) ----------------
__global__ void cast_f32_bf16(const float* __restrict__ in, u16* __restrict__ out, int n) {
  int i = (blockIdx.x * blockDim.x + threadIdx.x) * 4;
  if (i < n) {
    float4 v = *(const float4*)(in + i);
    u16x4 o = { f2bf(v.x), f2bf(v.y), f2bf(v.z), f2bf(v.w) };
    *(u16x4*)(out + i) = o;
  }
}

// ---------------- transpose + cast: in K x N fp32 -> out N x K bf16 ----------------
__global__ void transpose_cast(const float* __restrict__ in, u16* __restrict__ out, int K, int N) {
  __shared__ float tile[32][33];
  int n0 = blockIdx.x * 32, k0 = blockIdx.y * 32;
  int tx = threadIdx.x, ty = threadIdx.y;
  for (int i = ty; i < 32; i += 8)
    tile[i][tx] = in[(size_t)(k0 + i) * N + n0 + tx];
  __syncthreads();
  for (int i = ty; i < 32; i += 8)
    out[(size_t)(n0 + i) * K + k0 + tx] = f2bf(tile[tx][i]);
}

// ---------------- bf16 transpose for V ----------------
__global__ void vtrans(const u16* __restrict__ qkv, u16* __restrict__ Vt) {
  __shared__ u16 tile[32][33];
  int kv = blockIdx.z;
  int t0 = blockIdx.x * 32, d0 = blockIdx.y * 32;
  int tx = threadIdx.x, ty = threadIdx.y;
  for (int i = ty; i < 32; i += 8)
    tile[i][tx] = qkv[(size_t)(t0 + i) * QKVD + VOFF + kv * HD + d0 + tx];
  __syncthreads();
  for (int i = ty; i < 32; i += 8)
    Vt[(size_t)(kv * HD + d0 + i) * T_SEQ + t0 + tx] = tile[tx][i];
}

// ---------------- NeoX RoPE ----------------
__global__ void rope_kernel(u16* __restrict__ qkv, const int* __restrict__ positions) {
  int t = blockIdx.x;
  int h = blockIdx.y * 4 + (threadIdx.x >> 6);
  int i = threadIdx.x & 63;
  float pos = (float)positions[t];
  float freq = exp2f(-(float)i * (13.287712379549449f / 64.0f));
  float ang = pos * freq;
  float s, c;
  sincosf(ang, &s, &c);
  size_t off;
  if (h < NH) off = (size_t)t * QKVD + h * HD;
  else        off = (size_t)t * QKVD + KOFF + (h - NH) * HD;
  float x1 = bf2f(qkv[off + i]);
  float x2 = bf2f(qkv[off + 64 + i]);
  qkv[off + i]      = f2bf(x1 * c - x2 * s);
  qkv[off + 64 + i] = f2bf(x2 * c + x1 * s);
}

// ---------------- 256x256 8-phase GEMM: A(MxK) * B^T(NxK) -> C(MxN) ----------------
// half-tile = [128 rows][64 k] bf16, LDS layout linear with read-side XOR swizzle
// col16 ^= (row&7); staged via pre-swizzled global source (linear LDS dest).
__device__ inline void stage_half(const u16* __restrict__ G, int K, u16* lds, int w, int l) {
  const int rl = l >> 3;
  const int cs = ((l & 7) ^ rl) << 3;  // swizzled col (u16)
#pragma unroll
  for (int i = 0; i < 2; i++) {
    const u16* src = G + (size_t)(8 * w + 64 * i + rl) * K + cs;
    gl_lds16(src, lds + (8 * w + 64 * i) * 64);
  }
}

#define LDA(i, kk) a[i][kk] = *(const s16x8*)(Ah + (((i) * 16 + lr) * 64) + ((((kk) * 4 + lg) ^ xsw) << 3))
#define LDB(j, kk) b[j][kk] = *(const s16x8*)(Bh + (((j) * 16 + lr) * 64) + ((((kk) * 4 + lg) ^ xsw) << 3))
#define MFMA_Q(i0, j0)                                                        \
  _Pragma("unroll") for (int i = 0; i < 4; i++)                               \
  _Pragma("unroll") for (int j = 0; j < 2; j++)                               \
  _Pragma("unroll") for (int kk = 0; kk < 2; kk++)                            \
    acc[i0 + i][j0 + j] = __builtin_amdgcn_mfma_f32_16x16x32_bf16(            \
        a[i0 + i][kk], b[j0 + j][kk], acc[i0 + i][j0 + j], 0, 0, 0);

template <bool BF16OUT>
__global__ __launch_bounds__(512, 2) void gemm256(const u16* __restrict__ A,
                                                  const u16* __restrict__ B,
                                                  void* __restrict__ Cv,
                                                  int M, int N, int K) {
  __shared__ __align__(16) u16 As[2][2][128 * 64];
  __shared__ __align__(16) u16 Bs[2][2][128 * 64];
  const int tid = threadIdx.x;
  const int w = tid >> 6, l = tid & 63;
  const int lr = l & 15, lg = l >> 4;
  const int wm = w >> 2, wn = w & 3;
  const int xsw = lr & 7;
  const int bm = blockIdx.y * 256, bn = blockIdx.x * 256;
  const int NT = K >> 6;

  const u16* Ab0 = A + (size_t)bm * K;
  const u16* Ab1 = A + (size_t)(bm + 128) * K;
  const u16* Bb0 = B + (size_t)bn * K;
  const u16* Bb1 = B + (size_t)(bn + 128) * K;

  f32x4 acc[8][4] = {};

  // prologue: tile0 (4 halves) + tile1 A halves; leave tile1 A in flight
  stage_half(Ab0, K, As[0][0], w, l);
  stage_half(Ab1, K, As[0][1], w, l);
  stage_half(Bb0, K, Bs[0][0], w, l);
  stage_half(Bb1, K, Bs[0][1], w, l);
  if (NT > 1) {
    stage_half(Ab0 + 64, K, As[1][0], w, l);
    stage_half(Ab1 + 64, K, As[1][1], w, l);
    asm volatile("s_waitcnt vmcnt(4)" ::: "memory");
  } else {
    asm volatile("s_waitcnt vmcnt(0)" ::: "memory");
  }
  __builtin_amdgcn_s_barrier();

  for (int t = 0; t < NT; t++) {
    const int cur = t & 1;
    const u16* Ah = &As[cur][wm][0];
    const u16* Bh = &Bs[cur][wn >> 1][(wn & 1) * 64 * 64];
    s16x8 a[8][2], b[4][2];

    // ---------------- phase 1: reads a0-3,b0-1 | stage B0(t+1) | Q00 ----------------
#pragma unroll
    for (int i = 0; i < 4; i++) { LDA(i, 0); LDA(i, 1); }
    LDB(0, 0); LDB(0, 1); LDB(1, 0); LDB(1, 1);
    if (t + 1 < NT) stage_half(Bb0 + (size_t)(t + 1) * 64, K, Bs[cur ^ 1][0], w, l);
    __builtin_amdgcn_s_barrier();
    asm volatile("s_waitcnt lgkmcnt(0)" ::: "memory");
    __builtin_amdgcn_s_setprio(1);
    MFMA_Q(0, 0)
    __builtin_amdgcn_s_setprio(0);
    __builtin_amdgcn_s_barrier();

    // ---------------- phase 2: reads a4-7,b2-3 | stage B1(t+1) | Q01 ----------------
#pragma unroll
    for (int i = 4; i < 8; i++) { LDA(i, 0); LDA(i, 1); }
    LDB(2, 0); LDB(2, 1); LDB(3, 0); LDB(3, 1);
    if (t + 1 < NT) stage_half(Bb1 + (size_t)(t + 1) * 64, K, Bs[cur ^ 1][1], w, l);
    __builtin_amdgcn_s_barrier();
    asm volatile("s_waitcnt lgkmcnt(0)" ::: "memory");
    __builtin_amdgcn_s_setprio(1);
    MFMA_Q(0, 2)
    __builtin_amdgcn_s_setprio(0);
    __builtin_amdgcn_s_barrier();

    // ---------------- phase 3: stage A0(t+2) into current buf | Q11 ----------------
    if (t + 2 < NT) stage_half(Ab0 + (size_t)(t + 2) * 64, K, As[cur][0], w, l);
    __builtin_amdgcn_s_barrier();
    __builtin_amdgcn_s_setprio(1);
    MFMA_Q(4, 2)
    __builtin_amdgcn_s_setprio(0);
    __builtin_amdgcn_s_barrier();

    // ---------------- phase 4: stage A1(t+2) | counted vmcnt | Q10 ----------------
    if (t + 2 < NT) {
      stage_half(Ab1 + (size_t)(t + 2) * 64, K, As[cur][1], w, l);
      asm volatile("s_waitcnt vmcnt(4)" ::: "memory");
    } else {
      asm volatile("s_waitcnt vmcnt(0)" ::: "memory");
    }
    __builtin_amdgcn_s_barrier();
    __builtin_amdgcn_s_setprio(1);
    MFMA_Q(4, 0)
    __builtin_amdgcn_s_setprio(0);
    __builtin_amdgcn_s_barrier();
  }

  // epilogue
#pragma unroll
  for (int i = 0; i < 8; i++)
#pragma unroll
    for (int j = 0; j < 4; j++)
#pragma unroll
      for (int r = 0; r < 4; r++) {
        int row = bm + wm * 128 + i * 16 + lg * 4 + r;
        int col = bn + wn * 64 + j * 16 + lr;
        float v = acc[i][j][r];
        if (BF16OUT) ((u16*)Cv)[(size_t)row * N + col] = f2bf(v);
        else         ((float*)Cv)[(size_t)row * N + col] = v;
      }
}
#undef LDA
#undef LDB
#undef MFMA_Q

// ---------------- flash attention (unchanged from R2) ----------------
__device__ inline void stage_tiles(const u16* __restrict__ qkv, const u16* __restrict__ Vt,
                                   u16* Kb, u16* Vb, int kv0, int hkv, int w, int l) {
  const int krow_l = l >> 4;
  const int kcb = (l & 15) << 4;
  const int vrow_l = l >> 3;
  const int vcb = (l & 7) << 4;
#pragma unroll
  for (int c = 0; c < 4; c++) {
    int row = c * 16 + w * 4 + krow_l;
    const char* src = (const char*)(qkv + (size_t)(kv0 + row) * QKVD + KOFF + hkv * HD) +
                      (kcb ^ ((row & 7) << 4));
    gl_lds16(src, (char*)Kb + (c * 16 + w * 4) * 256);
  }
#pragma unroll
  for (int c = 0; c < 4; c++) {
    int row = c * 32 + w * 8 + vrow_l;
    const char* src = (const char*)(Vt + (size_t)(hkv * HD + row) * T_SEQ + kv0) +
                      (vcb ^ ((row & 7) << 4));
    gl_lds16(src, (char*)Vb + (c * 32 + w * 8) * 128);
  }
}

__global__ __launch_bounds__(256) void attn_fwd(const u16* __restrict__ qkv, const u16* __restrict__ Vt,
                                                u16* __restrict__ attnout) {
  __shared__ __align__(16) u16 Ks[2][64 * 128];
  __shared__ __align__(16) u16 Vs[2][128 * 64];
  __shared__ __align__(16) u16 plds[4][16 * 72];
  const int tid = threadIdx.x;
  const int w = tid >> 6, l = tid & 63;
  const int lr = l & 15, g = l >> 4;
  const int h = blockIdx.y;
  const int hkv = h >> 2;
  const int swzl = (lr & 7) << 4;
  const float scale = 0.08838834764831845f;
  u16* pw = &plds[w][0];

  for (int seg = 0; seg < 2; seg++) {
    const int qt = (seg == 0) ? blockIdx.x : (31 - blockIdx.x);
    const int q0 = qt * 64 + w * 16;
    const int q_abs = q0 + lr;

    s16x8 qf[4];
    const u16* qbase = qkv + (size_t)(q0 + lr) * QKVD + h * HD + g * 8;
#pragma unroll
    for (int kk = 0; kk < 4; kk++) qf[kk] = *(const s16x8*)(qbase + kk * 32);

    f32x4 acc_o[8] = {};
    float m_run = -__builtin_inff();
    float l_run = 0.0f;
    const int nt = qt + 1;

    stage_tiles(qkv, Vt, Ks[0], Vs[0], 0, hkv, w, l);
    asm volatile("s_waitcnt vmcnt(0)" ::: "memory");
    __syncthreads();
    int cur = 0;
    for (int kt = 0; kt < nt; kt++) {
      const int kv0 = kt * 64;
      if (kt + 1 < nt)
        stage_tiles(qkv, Vt, Ks[cur ^ 1], Vs[cur ^ 1], kv0 + 64, hkv, w, l);
      const bool masked = (kt == qt);

      f32x4 sa[4];
      const char* kb = (const char*)Ks[cur];
#pragma unroll
      for (int ct = 0; ct < 4; ct++) {
        f32x4 aa = {0.f, 0.f, 0.f, 0.f};
#pragma unroll
        for (int kk = 0; kk < 4; kk++) {
          s16x8 kf = *(const s16x8*)(kb + (ct * 16 + lr) * 256 + (((kk << 6) + (g << 4)) ^ swzl));
          aa = __builtin_amdgcn_mfma_f32_16x16x32_bf16(kf, qf[kk], aa, 0, 0, 0);
        }
        sa[ct] = aa;
      }

      float p[16];
      float pmax = -__builtin_inff();
#pragma unroll
      for (int ct = 0; ct < 4; ct++)
#pragma unroll
        for (int r = 0; r < 4; r++) {
          float s = sa[ct][r] * scale;
          if (masked) {
            int kv_abs = kv0 + ct * 16 + g * 4 + r;
            if (kv_abs > q_abs) s = -__builtin_inff();
          }
          p[ct * 4 + r] = s;
          pmax = fmaxf(pmax, s);
        }
      pmax = fmaxf(pmax, __shfl_xor(pmax, 16, 64));
      pmax = fmaxf(pmax, __shfl_xor(pmax, 32, 64));
      float m_new = fmaxf(m_run, pmax);
      float fac = __expf(m_run - m_new);
      float psum = 0.f;
#pragma unroll
      for (int x = 0; x < 16; x++) {
        float e = __expf(p[x] - m_new);
        p[x] = e;
        psum += e;
      }
      psum += __shfl_xor(psum, 16, 64);
      psum += __shfl_xor(psum, 32, 64);
      l_run = l_run * fac + psum;
      m_run = m_new;
      float fr[4];
#pragma unroll
      for (int r = 0; r < 4; r++) fr[r] = __shfl(fac, g * 4 + r, 64);
#pragma unroll
      for (int dt = 0; dt < 8; dt++)
#pragma unroll
        for (int r = 0; r < 4; r++) acc_o[dt][r] *= fr[r];

#pragma unroll
      for (int ct = 0; ct < 4; ct++) {
        u16x4 pk = { f2bf(p[ct * 4 + 0]), f2bf(p[ct * 4 + 1]), f2bf(p[ct * 4 + 2]), f2bf(p[ct * 4 + 3]) };
        *(u16x4*)(pw + lr * 72 + ct * 16 + g * 4) = pk;
      }
      asm volatile("s_waitcnt lgkmcnt(0)" ::: "memory");
      __builtin_amdgcn_sched_barrier(0);
      s16x8 pa0 = *(const s16x8*)(pw + lr * 72 + g * 8);
      s16x8 pa1 = *(const s16x8*)(pw + lr * 72 + 32 + g * 8);

      const char* vbb = (const char*)Vs[cur];
#pragma unroll
      for (int dt = 0; dt < 8; dt++) {
        s16x8 v0 = *(const s16x8*)(vbb + (dt * 16 + lr) * 128 + ((g << 4) ^ swzl));
        s16x8 v1 = *(const s16x8*)(vbb + (dt * 16 + lr) * 128 + ((64 + (g << 4)) ^ swzl));
        acc_o[dt] = __builtin_amdgcn_mfma_f32_16x16x32_bf16(pa0, v0, acc_o[dt], 0, 0, 0);
        acc_o[dt] = __builtin_amdgcn_mfma_f32_16x16x32_bf16(pa1, v1, acc_o[dt], 0, 0, 0);
      }
      asm volatile("s_waitcnt vmcnt(0)" ::: "memory");
      __syncthreads();
      cur ^= 1;
    }

    float ln[4];
#pragma unroll
    for (int r = 0; r < 4; r++) ln[r] = __shfl(l_run, g * 4 + r, 64);
#pragma unroll
    for (int dt = 0; dt < 8; dt++)
#pragma unroll
      for (int r = 0; r < 4; r++) {
        int row = q0 + g * 4 + r;
        int col = h * HD + dt * 16 + lr;
        attnout[(size_t)row * HID + col] = f2bf(acc_o[dt][r] / ln[r]);
      }
  }
}

extern "C" void kernel_launch(void* const* d_in, const int* in_sizes, int n_in,
                              void* d_out, int out_size, void* d_ws, size_t ws_size,
                              hipStream_t stream) {
  const int*   positions = (const int*)d_in[0];
  const float* X         = (const float*)d_in[1];
  const float* Wqkv      = (const float*)d_in[2];
  const float* Wo        = (const float*)d_in[3];
  float* out = (float*)d_out;

  char* ws = (char*)d_ws;
  size_t off = 0;
  u16* Xbf    = (u16*)(ws + off); off += (size_t)T_SEQ * HID * 2;
  u16* Wqkvt  = (u16*)(ws + off); off += (size_t)QKVD * HID * 2;
  u16* Wot    = (u16*)(ws + off); off += (size_t)HID * HID * 2;
  u16* qkv    = (u16*)(ws + off); off += (size_t)T_SEQ * QKVD * 2;
  u16* Vt     = (u16*)(ws + off); off += (size_t)NKV * HD * T_SEQ * 2;
  u16* attnb  = (u16*)(ws + off); off += (size_t)T_SEQ * HID * 2;

  cast_f32_bf16<<<dim3((T_SEQ * HID) / (256 * 4)), dim3(256), 0, stream>>>(X, Xbf, T_SEQ * HID);
  transpose_cast<<<dim3(QKVD / 32, HID / 32), dim3(32, 8), 0, stream>>>(Wqkv, Wqkvt, HID, QKVD);
  transpose_cast<<<dim3(HID / 32, HID / 32), dim3(32, 8), 0, stream>>>(Wo, Wot, HID, HID);
  gemm256<true><<<dim3(QKVD / 256, T_SEQ / 256), dim3(512), 0, stream>>>(Xbf, Wqkvt, qkv, T_SEQ, QKVD, HID);
  rope_kernel<<<dim3(T_SEQ, 10), dim3(256), 0, stream>>>(qkv, positions);
  vtrans<<<dim3(T_SEQ / 32, HD / 32, NKV), dim3(32, 8), 0, stream>>>(qkv, Vt);
  attn_fwd<<<dim3(16, 32), dim3(256), 0, stream>>>(qkv, Vt, attnb);
  gemm256<false><<<dim3(HID / 256, T_SEQ / 256), dim3(512), 0, stream>>>(attnb, Wot, out, T_SEQ, HID, HID);
}

// Round 4
// 536.470 us; speedup vs baseline: 1.0918x; 1.0918x over previous
//
#include <hip/hip_runtime.h>
#include <hip/hip_bf16.h>
#include <math.h>

#define T_SEQ 2048
#define HID   4096
#define NH    32
#define NKV   8
#define HD    128
#define QKVD  6144
#define KOFF  4096
#define VOFF  5120

typedef unsigned short u16;
typedef unsigned int   u32;
typedef __attribute__((ext_vector_type(4))) float f32x4;
typedef __attribute__((ext_vector_type(8))) short s16x8;
typedef __attribute__((ext_vector_type(4))) unsigned short u16x4;

__device__ inline u16 f2bf(float f) {
  u32 u = __float_as_uint(f);
  u32 r = u + 0x7FFFu + ((u >> 16) & 1u);
  return (u16)(r >> 16);
}
__device__ inline float bf2f(u16 h) { return __uint_as_float(((u32)h) << 16); }

__device__ inline void gl_lds16(const void* g, void* l) {
  __builtin_amdgcn_global_load_lds((const __attribute__((address_space(1))) void*)g,
                                   (__attribute__((address_space(3))) void*)l, 16, 0, 0);
}

// ---------------- cast fp32 -> bf16 (vectorized) ----------------
__global__ void cast_f32_bf16(const float* __restrict__ in, u16* __restrict__ out, int n) {
  int i = (blockIdx.x * blockDim.x + threadIdx.x) * 4;
  if (i < n) {
    float4 v = *(const float4*)(in + i);
    u16x4 o = { f2bf(v.x), f2bf(v.y), f2bf(v.z), f2bf(v.w) };
    *(u16x4*)(out + i) = o;
  }
}

// ---------------- transpose + cast: in K x N fp32 -> out N x K bf16 ----------------
__global__ void transpose_cast(const float* __restrict__ in, u16* __restrict__ out, int K, int N) {
  __shared__ float tile[32][33];
  int n0 = blockIdx.x * 32, k0 = blockIdx.y * 32;
  int tx = threadIdx.x, ty = threadIdx.y;
  for (int i = ty; i < 32; i += 8)
    tile[i][tx] = in[(size_t)(k0 + i) * N + n0 + tx];
  __syncthreads();
  for (int i = ty; i < 32; i += 8)
    out[(size_t)(n0 + i) * K + k0 + tx] = f2bf(tile[tx][i]);
}

// ---------------- bf16 transpose for V ----------------
__global__ void vtrans(const u16* __restrict__ qkv, u16* __restrict__ Vt) {
  __shared__ u16 tile[32][33];
  int kv = blockIdx.z;
  int t0 = blockIdx.x * 32, d0 = blockIdx.y * 32;
  int tx = threadIdx.x, ty = threadIdx.y;
  for (int i = ty; i < 32; i += 8)
    tile[i][tx] = qkv[(size_t)(t0 + i) * QKVD + VOFF + kv * HD + d0 + tx];
  __syncthreads();
  for (int i = ty; i < 32; i += 8)
    Vt[(size_t)(kv * HD + d0 + i) * T_SEQ + t0 + tx] = tile[tx][i];
}

// ---------------- NeoX RoPE ----------------
__global__ void rope_kernel(u16* __restrict__ qkv, const int* __restrict__ positions) {
  int t = blockIdx.x;
  int h = blockIdx.y * 4 + (threadIdx.x >> 6);
  int i = threadIdx.x & 63;
  float pos = (float)positions[t];
  float freq = exp2f(-(float)i * (13.287712379549449f / 64.0f));
  float ang = pos * freq;
  float s, c;
  sincosf(ang, &s, &c);
  size_t off;
  if (h < NH) off = (size_t)t * QKVD + h * HD;
  else        off = (size_t)t * QKVD + KOFF + (h - NH) * HD;
  float x1 = bf2f(qkv[off + i]);
  float x2 = bf2f(qkv[off + 64 + i]);
  qkv[off + i]      = f2bf(x1 * c - x2 * s);
  qkv[off + 64 + i] = f2bf(x2 * c + x1 * s);
}

// ---------------- shared GEMM helpers ----------------
// stage one [64 rows][64 k] u16 unit; all 512 threads issue 1 gl_lds (16B) each.
// LDS[row][c8] = G[row][c8 ^ (row&7)]  (read side applies the same XOR)
__device__ inline void stage_unit(const u16* __restrict__ G, int K, u16* lds, int w, int l) {
  const int rl = l >> 3;                       // 0..7
  const int row = 8 * w + rl;                  // 0..63 ; row&7 == rl
  const int cs = ((l & 7) ^ rl) << 3;          // swizzled source col (u16)
  gl_lds16(G + (size_t)row * K + cs, lds + 8 * w * 64);
}

#define RD(base, row) (*(const s16x8*)((base) + (size_t)(row) * 64 + ((((kk) * 4 + lg) ^ xsw) << 3)))
#define MM(i, j) acc[i][j] = __builtin_amdgcn_mfma_f32_16x16x32_bf16(a[i][kk], b[j][kk], acc[i][j], 0, 0, 0)

// ---------------- GEMM1: 256x192 tile, BK=64, 4-phase, 2-buffer (A t+2 into cur) ----------------
// A (MxK), B^T (NxK) -> C (MxN) bf16. grid (N/192, M/256) = (32,8) = 256 blocks.
__global__ __launch_bounds__(512, 2) void gemm_qkv(const u16* __restrict__ A, const u16* __restrict__ B,
                                                   u16* __restrict__ C, int M, int N, int K) {
  __shared__ __align__(16) u16 As[2][256 * 64];
  __shared__ __align__(16) u16 Bs[2][192 * 64];
  const int tid = threadIdx.x;
  const int w = tid >> 6, l = tid & 63;
  const int lr = l & 15, lg = l >> 4;
  const int wm = w >> 2, wn = w & 3;
  const int xsw = lr & 7;
  const int bm = blockIdx.y * 256, bn = blockIdx.x * 192;
  const int NT = K >> 6;

  f32x4 acc[8][3] = {};
  s16x8 a[8][2], b[3][2];

  // prologue: tile0 (A 4 units + B 3) then A of tile1 (4) left in flight
#pragma unroll
  for (int u = 0; u < 4; u++) stage_unit(A + (size_t)(bm + 64 * u) * K, K, As[0] + u * 4096, w, l);
#pragma unroll
  for (int u = 0; u < 3; u++) stage_unit(B + (size_t)(bn + 64 * u) * K, K, Bs[0] + u * 4096, w, l);
#pragma unroll
  for (int u = 0; u < 4; u++) stage_unit(A + (size_t)(bm + 64 * u) * K + 64, K, As[1] + u * 4096, w, l);
  asm volatile("s_waitcnt vmcnt(4)" ::: "memory");
  __builtin_amdgcn_s_barrier();

  for (int t = 0; t < NT; t++) {
    const int cur = t & 1;
    const u16* Ah = As[cur];
    const u16* Bh = Bs[cur];
    const int k1 = (t + 1) * 64, k2 = (t + 2) * 64;

    // ---- phase 1: read a0-3,b0-1 | stage B0,B1(t+1)->other | MFMA i0-3 x j0-1 ----
#pragma unroll
    for (int kk = 0; kk < 2; kk++) {
#pragma unroll
      for (int i = 0; i < 4; i++) a[i][kk] = RD(Ah, wm * 128 + i * 16 + lr);
#pragma unroll
      for (int j = 0; j < 2; j++) b[j][kk] = RD(Bh, wn * 48 + j * 16 + lr);
    }
    if (t + 1 < NT) {
      stage_unit(B + (size_t)(bn) * K + k1, K, Bs[cur ^ 1] + 0 * 4096, w, l);
      stage_unit(B + (size_t)(bn + 64) * K + k1, K, Bs[cur ^ 1] + 1 * 4096, w, l);
    }
    __builtin_amdgcn_s_barrier();
    asm volatile("s_waitcnt lgkmcnt(0)" ::: "memory");
    __builtin_amdgcn_sched_barrier(0);
    __builtin_amdgcn_s_setprio(1);
#pragma unroll
    for (int kk = 0; kk < 2; kk++)
#pragma unroll
      for (int i = 0; i < 4; i++) { MM(i, 0); MM(i, 1); }
    __builtin_amdgcn_s_setprio(0);
    __builtin_amdgcn_s_barrier();

    // ---- phase 2: read a4-7,b2 | stage B2(t+1) | MFMA (i0-7) x j2 ----
#pragma unroll
    for (int kk = 0; kk < 2; kk++) {
#pragma unroll
      for (int i = 4; i < 8; i++) a[i][kk] = RD(Ah, wm * 128 + i * 16 + lr);
      b[2][kk] = RD(Bh, wn * 48 + 2 * 16 + lr);
    }
    if (t + 1 < NT)
      stage_unit(B + (size_t)(bn + 128) * K + k1, K, Bs[cur ^ 1] + 2 * 4096, w, l);
    __builtin_amdgcn_s_barrier();
    asm volatile("s_waitcnt lgkmcnt(0)" ::: "memory");
    __builtin_amdgcn_sched_barrier(0);
    __builtin_amdgcn_s_setprio(1);
#pragma unroll
    for (int kk = 0; kk < 2; kk++)
#pragma unroll
      for (int i = 0; i < 8; i++) MM(i, 2);
    __builtin_amdgcn_s_setprio(0);
    __builtin_amdgcn_s_barrier();

    // ---- phase 3: stage A0,A1(t+2)->cur | MFMA i4-7 x j0 ----
    if (t + 2 < NT) {
      stage_unit(A + (size_t)(bm) * K + k2, K, As[cur] + 0 * 4096, w, l);
      stage_unit(A + (size_t)(bm + 64) * K + k2, K, As[cur] + 1 * 4096, w, l);
    }
    __builtin_amdgcn_s_barrier();
    __builtin_amdgcn_s_setprio(1);
#pragma unroll
    for (int kk = 0; kk < 2; kk++)
#pragma unroll
      for (int i = 4; i < 8; i++) MM(i, 0);
    __builtin_amdgcn_s_setprio(0);
    __builtin_amdgcn_s_barrier();

    // ---- phase 4: stage A2,A3(t+2) | counted vmcnt | MFMA i4-7 x j1 ----
    if (t + 2 < NT) {
      stage_unit(A + (size_t)(bm + 128) * K + k2, K, As[cur] + 2 * 4096, w, l);
      stage_unit(A + (size_t)(bm + 192) * K + k2, K, As[cur] + 3 * 4096, w, l);
      asm volatile("s_waitcnt vmcnt(4)" ::: "memory");
    } else {
      asm volatile("s_waitcnt vmcnt(0)" ::: "memory");
    }
    __builtin_amdgcn_s_barrier();
    __builtin_amdgcn_s_setprio(1);
#pragma unroll
    for (int kk = 0; kk < 2; kk++)
#pragma unroll
      for (int i = 4; i < 8; i++) MM(i, 1);
    __builtin_amdgcn_s_setprio(0);
    __builtin_amdgcn_s_barrier();
  }

#pragma unroll
  for (int i = 0; i < 8; i++)
#pragma unroll
    for (int j = 0; j < 3; j++)
#pragma unroll
      for (int r = 0; r < 4; r++) {
        int row = bm + wm * 128 + i * 16 + lg * 4 + r;
        int col = bn + wn * 48 + j * 16 + lr;
        C[(size_t)row * N + col] = f2bf(acc[i][j][r]);
      }
}

// ---------------- GEMM2: 128x256 tile, BK=64, 2-phase, TRIPLE buffer ----------------
// A (MxK), B^T (NxK) -> C (MxN) f32. grid (N/256, M/128) = (16,16) = 256 blocks.
__global__ __launch_bounds__(512, 2) void gemm_out(const u16* __restrict__ A, const u16* __restrict__ B,
                                                   float* __restrict__ C, int M, int N, int K) {
  __shared__ __align__(16) u16 As3[3 * 128 * 64];
  __shared__ __align__(16) u16 Bs3[3 * 256 * 64];
  const int tid = threadIdx.x;
  const int w = tid >> 6, l = tid & 63;
  const int lr = l & 15, lg = l >> 4;
  const int wm = w >> 2, wn = w & 3;
  const int xsw = lr & 7;
  const int bm = blockIdx.y * 128, bn = blockIdx.x * 256;
  const int NT = K >> 6;

  f32x4 acc[4][4] = {};
  s16x8 a[4][2], b[4][2];

  // prologue: tile0 -> buf0, tile1 -> buf1 (6 units each)
#pragma unroll
  for (int u = 0; u < 2; u++) stage_unit(A + (size_t)(bm + 64 * u) * K, K, As3 + u * 4096, w, l);
#pragma unroll
  for (int u = 0; u < 4; u++) stage_unit(B + (size_t)(bn + 64 * u) * K, K, Bs3 + u * 4096, w, l);
#pragma unroll
  for (int u = 0; u < 2; u++) stage_unit(A + (size_t)(bm + 64 * u) * K + 64, K, As3 + 8192 + u * 4096, w, l);
#pragma unroll
  for (int u = 0; u < 4; u++) stage_unit(B + (size_t)(bn + 64 * u) * K + 64, K, Bs3 + 16384 + u * 4096, w, l);
  asm volatile("s_waitcnt vmcnt(6)" ::: "memory");
  __builtin_amdgcn_s_barrier();

  int cur = 0;
  for (int t = 0; t < NT; t++) {
    const u16* Ah = As3 + cur * 8192;
    const u16* Bh = Bs3 + cur * 16384;
    int sb = cur + 2; if (sb >= 3) sb -= 3;
    u16* Asb = As3 + sb * 8192;
    u16* Bsb = Bs3 + sb * 16384;
    const int k2 = (t + 2) * 64;

    // ---- phase 1: read all a, b0-1 | stage B0,B1,B2(t+2) | MFMA i0-3 x j0-1 ----
#pragma unroll
    for (int kk = 0; kk < 2; kk++) {
#pragma unroll
      for (int i = 0; i < 4; i++) a[i][kk] = RD(Ah, wm * 64 + i * 16 + lr);
#pragma unroll
      for (int j = 0; j < 2; j++) b[j][kk] = RD(Bh, wn * 64 + j * 16 + lr);
    }
    if (t + 2 < NT) {
      stage_unit(B + (size_t)(bn) * K + k2, K, Bsb + 0 * 4096, w, l);
      stage_unit(B + (size_t)(bn + 64) * K + k2, K, Bsb + 1 * 4096, w, l);
      stage_unit(B + (size_t)(bn + 128) * K + k2, K, Bsb + 2 * 4096, w, l);
    }
    __builtin_amdgcn_s_barrier();
    asm volatile("s_waitcnt lgkmcnt(0)" ::: "memory");
    __builtin_amdgcn_sched_barrier(0);
    __builtin_amdgcn_s_setprio(1);
#pragma unroll
    for (int kk = 0; kk < 2; kk++)
#pragma unroll
      for (int i = 0; i < 4; i++) { MM(i, 0); MM(i, 1); }
    __builtin_amdgcn_s_setprio(0);
    __builtin_amdgcn_s_barrier();

    // ---- phase 2: read b2-3 | stage B3,A0,A1(t+2) | counted vmcnt(6) | MFMA i0-3 x j2-3 ----
#pragma unroll
    for (int kk = 0; kk < 2; kk++)
#pragma unroll
      for (int j = 2; j < 4; j++) b[j][kk] = RD(Bh, wn * 64 + j * 16 + lr);
    if (t + 2 < NT) {
      stage_unit(B + (size_t)(bn + 192) * K + k2, K, Bsb + 3 * 4096, w, l);
      stage_unit(A + (size_t)(bm) * K + k2, K, Asb + 0 * 4096, w, l);
      stage_unit(A + (size_t)(bm + 64) * K + k2, K, Asb + 1 * 4096, w, l);
      asm volatile("s_waitcnt vmcnt(6)" ::: "memory");
    } else {
      asm volatile("s_waitcnt vmcnt(0)" ::: "memory");
    }
    __builtin_amdgcn_s_barrier();
    asm volatile("s_waitcnt lgkmcnt(0)" ::: "memory");
    __builtin_amdgcn_sched_barrier(0);
    __builtin_amdgcn_s_setprio(1);
#pragma unroll
    for (int kk = 0; kk < 2; kk++)
#pragma unroll
      for (int i = 0; i < 4; i++) { MM(i, 2); MM(i, 3); }
    __builtin_amdgcn_s_setprio(0);
    __builtin_amdgcn_s_barrier();

    cur = (cur == 2) ? 0 : cur + 1;
  }

#pragma unroll
  for (int i = 0; i < 4; i++)
#pragma unroll
    for (int j = 0; j < 4; j++)
#pragma unroll
      for (int r = 0; r < 4; r++) {
        int row = bm + wm * 64 + i * 16 + lg * 4 + r;
        int col = bn + wn * 64 + j * 16 + lr;
        C[(size_t)row * N + col] = acc[i][j][r];
      }
}
#undef RD
#undef MM

// ---------------- flash attention (unchanged) ----------------
__device__ inline void stage_tiles(const u16* __restrict__ qkv, const u16* __restrict__ Vt,
                                   u16* Kb, u16* Vb, int kv0, int hkv, int w, int l) {
  const int krow_l = l >> 4;
  const int kcb = (l & 15) << 4;
  const int vrow_l = l >> 3;
  const int vcb = (l & 7) << 4;
#pragma unroll
  for (int c = 0; c < 4; c++) {
    int row = c * 16 + w * 4 + krow_l;
    const char* src = (const char*)(qkv + (size_t)(kv0 + row) * QKVD + KOFF + hkv * HD) +
                      (kcb ^ ((row & 7) << 4));
    gl_lds16(src, (char*)Kb + (c * 16 + w * 4) * 256);
  }
#pragma unroll
  for (int c = 0; c < 4; c++) {
    int row = c * 32 + w * 8 + vrow_l;
    const char* src = (const char*)(Vt + (size_t)(hkv * HD + row) * T_SEQ + kv0) +
                      (vcb ^ ((row & 7) << 4));
    gl_lds16(src, (char*)Vb + (c * 32 + w * 8) * 128);
  }
}

__global__ __launch_bounds__(256) void attn_fwd(const u16* __restrict__ qkv, const u16* __restrict__ Vt,
                                                u16* __restrict__ attnout) {
  __shared__ __align__(16) u16 Ks[2][64 * 128];
  __shared__ __align__(16) u16 Vs[2][128 * 64];
  __shared__ __align__(16) u16 plds[4][16 * 72];
  const int tid = threadIdx.x;
  const int w = tid >> 6, l = tid & 63;
  const int lr = l & 15, g = l >> 4;
  const int h = blockIdx.y;
  const int hkv = h >> 2;
  const int swzl = (lr & 7) << 4;
  const float scale = 0.08838834764831845f;
  u16* pw = &plds[w][0];

  for (int seg = 0; seg < 2; seg++) {
    const int qt = (seg == 0) ? blockIdx.x : (31 - blockIdx.x);
    const int q0 = qt * 64 + w * 16;
    const int q_abs = q0 + lr;

    s16x8 qf[4];
    const u16* qbase = qkv + (size_t)(q0 + lr) * QKVD + h * HD + g * 8;
#pragma unroll
    for (int kk = 0; kk < 4; kk++) qf[kk] = *(const s16x8*)(qbase + kk * 32);

    f32x4 acc_o[8] = {};
    float m_run = -__builtin_inff();
    float l_run = 0.0f;
    const int nt = qt + 1;

    stage_tiles(qkv, Vt, Ks[0], Vs[0], 0, hkv, w, l);
    asm volatile("s_waitcnt vmcnt(0)" ::: "memory");
    __syncthreads();
    int cur = 0;
    for (int kt = 0; kt < nt; kt++) {
      const int kv0 = kt * 64;
      if (kt + 1 < nt)
        stage_tiles(qkv, Vt, Ks[cur ^ 1], Vs[cur ^ 1], kv0 + 64, hkv, w, l);
      const bool masked = (kt == qt);

      f32x4 sa[4];
      const char* kb = (const char*)Ks[cur];
#pragma unroll
      for (int ct = 0; ct < 4; ct++) {
        f32x4 aa = {0.f, 0.f, 0.f, 0.f};
#pragma unroll
        for (int kk = 0; kk < 4; kk++) {
          s16x8 kf = *(const s16x8*)(kb + (ct * 16 + lr) * 256 + (((kk << 6) + (g << 4)) ^ swzl));
          aa = __builtin_amdgcn_mfma_f32_16x16x32_bf16(kf, qf[kk], aa, 0, 0, 0);
        }
        sa[ct] = aa;
      }

      float p[16];
      float pmax = -__builtin_inff();
#pragma unroll
      for (int ct = 0; ct < 4; ct++)
#pragma unroll
        for (int r = 0; r < 4; r++) {
          float s = sa[ct][r] * scale;
          if (masked) {
            int kv_abs = kv0 + ct * 16 + g * 4 + r;
            if (kv_abs > q_abs) s = -__builtin_inff();
          }
          p[ct * 4 + r] = s;
          pmax = fmaxf(pmax, s);
        }
      pmax = fmaxf(pmax, __shfl_xor(pmax, 16, 64));
      pmax = fmaxf(pmax, __shfl_xor(pmax, 32, 64));
      float m_new = fmaxf(m_run, pmax);
      float fac = __expf(m_run - m_new);
      float psum = 0.f;
#pragma unroll
      for (int x = 0; x < 16; x++) {
        float e = __expf(p[x] - m_new);
        p[x] = e;
        psum += e;
      }
      psum += __shfl_xor(psum, 16, 64);
      psum += __shfl_xor(psum, 32, 64);
      l_run = l_run * fac + psum;
      m_run = m_new;
      float fr[4];
#pragma unroll
      for (int r = 0; r < 4; r++) fr[r] = __shfl(fac, g * 4 + r, 64);
#pragma unroll
      for (int dt = 0; dt < 8; dt++)
#pragma unroll
        for (int r = 0; r < 4; r++) acc_o[dt][r] *= fr[r];

#pragma unroll
      for (int ct = 0; ct < 4; ct++) {
        u16x4 pk = { f2bf(p[ct * 4 + 0]), f2bf(p[ct * 4 + 1]), f2bf(p[ct * 4 + 2]), f2bf(p[ct * 4 + 3]) };
        *(u16x4*)(pw + lr * 72 + ct * 16 + g * 4) = pk;
      }
      asm volatile("s_waitcnt lgkmcnt(0)" ::: "memory");
      __builtin_amdgcn_sched_barrier(0);
      s16x8 pa0 = *(const s16x8*)(pw + lr * 72 + g * 8);
      s16x8 pa1 = *(const s16x8*)(pw + lr * 72 + 32 + g * 8);

      const char* vbb = (const char*)Vs[cur];
#pragma unroll
      for (int dt = 0; dt < 8; dt++) {
        s16x8 v0 = *(const s16x8*)(vbb + (dt * 16 + lr) * 128 + ((g << 4) ^ swzl));
        s16x8 v1 = *(const s16x8*)(vbb + (dt * 16 + lr) * 128 + ((64 + (g << 4)) ^ swzl));
        acc_o[dt] = __builtin_amdgcn_mfma_f32_16x16x32_bf16(pa0, v0, acc_o[dt], 0, 0, 0);
        acc_o[dt] = __builtin_amdgcn_mfma_f32_16x16x32_bf16(pa1, v1, acc_o[dt], 0, 0, 0);
      }
      asm volatile("s_waitcnt vmcnt(0)" ::: "memory");
      __syncthreads();
      cur ^= 1;
    }

    float ln[4];
#pragma unroll
    for (int r = 0; r < 4; r++) ln[r] = __shfl(l_run, g * 4 + r, 64);
#pragma unroll
    for (int dt = 0; dt < 8; dt++)
#pragma unroll
      for (int r = 0; r < 4; r++) {
        int row = q0 + g * 4 + r;
        int col = h * HD + dt * 16 + lr;
        attnout[(size_t)row * HID + col] = f2bf(acc_o[dt][r] / ln[r]);
      }
  }
}

extern "C" void kernel_launch(void* const* d_in, const int* in_sizes, int n_in,
                              void* d_out, int out_size, void* d_ws, size_t ws_size,
                              hipStream_t stream) {
  const int*   positions = (const int*)d_in[0];
  const float* X         = (const float*)d_in[1];
  const float* Wqkv      = (const float*)d_in[2];
  const float* Wo        = (const float*)d_in[3];
  float* out = (float*)d_out;

  char* ws = (char*)d_ws;
  size_t off = 0;
  u16* Xbf    = (u16*)(ws + off); off += (size_t)T_SEQ * HID * 2;
  u16* Wqkvt  = (u16*)(ws + off); off += (size_t)QKVD * HID * 2;
  u16* Wot    = (u16*)(ws + off); off += (size_t)HID * HID * 2;
  u16* qkv    = (u16*)(ws + off); off += (size_t)T_SEQ * QKVD * 2;
  u16* Vt     = (u16*)(ws + off); off += (size_t)NKV * HD * T_SEQ * 2;
  u16* attnb  = (u16*)(ws + off); off += (size_t)T_SEQ * HID * 2;

  cast_f32_bf16<<<dim3((T_SEQ * HID) / (256 * 4)), dim3(256), 0, stream>>>(X, Xbf, T_SEQ * HID);
  transpose_cast<<<dim3(QKVD / 32, HID / 32), dim3(32, 8), 0, stream>>>(Wqkv, Wqkvt, HID, QKVD);
  transpose_cast<<<dim3(HID / 32, HID / 32), dim3(32, 8), 0, stream>>>(Wo, Wot, HID, HID);
  gemm_qkv<<<dim3(QKVD / 192, T_SEQ / 256), dim3(512), 0, stream>>>(Xbf, Wqkvt, qkv, T_SEQ, QKVD, HID);
  rope_kernel<<<dim3(T_SEQ, 10), dim3(256), 0, stream>>>(qkv, positions);
  vtrans<<<dim3(T_SEQ / 32, HD / 32, NKV), dim3(32, 8), 0, stream>>>(qkv, Vt);
  attn_fwd<<<dim3(16, 32), dim3(256), 0, stream>>>(qkv, Vt, attnb);
  gemm_out<<<dim3(HID / 256, T_SEQ / 128), dim3(512), 0, stream>>>(attnb, Wot, out, T_SEQ, HID, HID);
}

// Round 5
// 521.901 us; speedup vs baseline: 1.1223x; 1.0279x over previous
//
#include <hip/hip_runtime.h>
#include <hip/hip_bf16.h>
#include <math.h>

#define T_SEQ 2048
#define HID   4096
#define NH    32
#define NKV   8
#define HD    128
#define QKVD  6144
#define KOFF  4096
#define VOFF  5120

typedef unsigned short u16;
typedef unsigned int   u32;
typedef __attribute__((ext_vector_type(4))) float f32x4;
typedef __attribute__((ext_vector_type(16))) float f32x16;
typedef __attribute__((ext_vector_type(8))) short s16x8;
typedef __attribute__((ext_vector_type(4))) unsigned short u16x4;

__device__ inline u16 f2bf(float f) {
  u32 u = __float_as_uint(f);
  u32 r = u + 0x7FFFu + ((u >> 16) & 1u);
  return (u16)(r >> 16);
}
__device__ inline float bf2f(u16 h) { return __uint_as_float(((u32)h) << 16); }

__device__ inline void gl_lds16(const void* g, void* l) {
  __builtin_amdgcn_global_load_lds((const __attribute__((address_space(1))) void*)g,
                                   (__attribute__((address_space(3))) void*)l, 16, 0, 0);
}

__device__ inline u32 cvtpk_bf16(float a, float b) {
  u32 r;
  asm("v_cvt_pk_bf16_f32 %0, %1, %2" : "=v"(r) : "v"(a), "v"(b));
  return r;
}

// ---------------- cast fp32 -> bf16 (vectorized) ----------------
__global__ void cast_f32_bf16(const float* __restrict__ in, u16* __restrict__ out, int n) {
  int i = (blockIdx.x * blockDim.x + threadIdx.x) * 4;
  if (i < n) {
    float4 v = *(const float4*)(in + i);
    u16x4 o = { f2bf(v.x), f2bf(v.y), f2bf(v.z), f2bf(v.w) };
    *(u16x4*)(out + i) = o;
  }
}

// ---------------- transpose + cast: in K x N fp32 -> out N x K bf16 ----------------
__global__ void transpose_cast(const float* __restrict__ in, u16* __restrict__ out, int K, int N) {
  __shared__ float tile[32][33];
  int n0 = blockIdx.x * 32, k0 = blockIdx.y * 32;
  int tx = threadIdx.x, ty = threadIdx.y;
  for (int i = ty; i < 32; i += 8)
    tile[i][tx] = in[(size_t)(k0 + i) * N + n0 + tx];
  __syncthreads();
  for (int i = ty; i < 32; i += 8)
    out[(size_t)(n0 + i) * K + k0 + tx] = f2bf(tile[tx][i]);
}

// ---------------- bf16 transpose for V, with kv mid-quad permutation ----------------
// Within each group of 16 kv positions, quads are stored in order {0,2,1,3} so that
// the 32x32x16 MFMA B-fragment (lane hi-half holds k-elems 8..15) lines up with the
// per-lane P residency after swapped QK^T (kv = (r&3)+8*(r>>2)+4*hi). Involution.
__global__ void vtrans(const u16* __restrict__ qkv, u16* __restrict__ Vt) {
  __shared__ u16 tile[32][33];
  int kv = blockIdx.z;
  int t0 = blockIdx.x * 32, d0 = blockIdx.y * 32;
  int tx = threadIdx.x, ty = threadIdx.y;
  for (int i = ty; i < 32; i += 8)
    tile[i][tx] = qkv[(size_t)(t0 + i) * QKVD + VOFF + kv * HD + d0 + tx];
  __syncthreads();
  int txp = (tx & 16) | (tx & 3) | ((tx & 4) << 1) | ((tx & 8) >> 1);
  for (int i = ty; i < 32; i += 8)
    Vt[(size_t)(kv * HD + d0 + i) * T_SEQ + t0 + txp] = tile[tx][i];
}

// ---------------- NeoX RoPE ----------------
__global__ void rope_kernel(u16* __restrict__ qkv, const int* __restrict__ positions) {
  int t = blockIdx.x;
  int h = blockIdx.y * 4 + (threadIdx.x >> 6);
  int i = threadIdx.x & 63;
  float pos = (float)positions[t];
  float freq = exp2f(-(float)i * (13.287712379549449f / 64.0f));
  float ang = pos * freq;
  float s, c;
  sincosf(ang, &s, &c);
  size_t off;
  if (h < NH) off = (size_t)t * QKVD + h * HD;
  else        off = (size_t)t * QKVD + KOFF + (h - NH) * HD;
  float x1 = bf2f(qkv[off + i]);
  float x2 = bf2f(qkv[off + 64 + i]);
  qkv[off + i]      = f2bf(x1 * c - x2 * s);
  qkv[off + 64 + i] = f2bf(x2 * c + x1 * s);
}

// ---------------- shared GEMM helpers ----------------
__device__ inline void stage_unit(const u16* __restrict__ G, int K, u16* lds, int w, int l) {
  const int rl = l >> 3;
  const int cs = ((l & 7) ^ rl) << 3;
  gl_lds16(G + (size_t)(8 * w + rl) * K + cs, lds + 8 * w * 64);
}

#define RD(base, row) (*(const s16x8*)((base) + (size_t)(row) * 64 + ((((kk) * 4 + lg) ^ xsw) << 3)))
#define MM(i, j) acc[i][j] = __builtin_amdgcn_mfma_f32_16x16x32_bf16(a[i][kk], b[j][kk], acc[i][j], 0, 0, 0)

// ---------------- GEMM1: 256x192 tile, BK=64, 4-phase ----------------
__global__ __launch_bounds__(512, 2) void gemm_qkv(const u16* __restrict__ A, const u16* __restrict__ B,
                                                   u16* __restrict__ C, int M, int N, int K) {
  __shared__ __align__(16) u16 As[2][256 * 64];
  __shared__ __align__(16) u16 Bs[2][192 * 64];
  const int tid = threadIdx.x;
  const int w = tid >> 6, l = tid & 63;
  const int lr = l & 15, lg = l >> 4;
  const int wm = w >> 2, wn = w & 3;
  const int xsw = lr & 7;
  const int bm = blockIdx.y * 256, bn = blockIdx.x * 192;
  const int NT = K >> 6;

  f32x4 acc[8][3] = {};
  s16x8 a[8][2], b[3][2];

#pragma unroll
  for (int u = 0; u < 4; u++) stage_unit(A + (size_t)(bm + 64 * u) * K, K, As[0] + u * 4096, w, l);
#pragma unroll
  for (int u = 0; u < 3; u++) stage_unit(B + (size_t)(bn + 64 * u) * K, K, Bs[0] + u * 4096, w, l);
#pragma unroll
  for (int u = 0; u < 4; u++) stage_unit(A + (size_t)(bm + 64 * u) * K + 64, K, As[1] + u * 4096, w, l);
  asm volatile("s_waitcnt vmcnt(4)" ::: "memory");
  __builtin_amdgcn_s_barrier();

  for (int t = 0; t < NT; t++) {
    const int cur = t & 1;
    const u16* Ah = As[cur];
    const u16* Bh = Bs[cur];
    const int k1 = (t + 1) * 64, k2 = (t + 2) * 64;

#pragma unroll
    for (int kk = 0; kk < 2; kk++) {
#pragma unroll
      for (int i = 0; i < 4; i++) a[i][kk] = RD(Ah, wm * 128 + i * 16 + lr);
#pragma unroll
      for (int j = 0; j < 2; j++) b[j][kk] = RD(Bh, wn * 48 + j * 16 + lr);
    }
    if (t + 1 < NT) {
      stage_unit(B + (size_t)(bn) * K + k1, K, Bs[cur ^ 1] + 0 * 4096, w, l);
      stage_unit(B + (size_t)(bn + 64) * K + k1, K, Bs[cur ^ 1] + 1 * 4096, w, l);
    }
    __builtin_amdgcn_s_barrier();
    asm volatile("s_waitcnt lgkmcnt(0)" ::: "memory");
    __builtin_amdgcn_sched_barrier(0);
    __builtin_amdgcn_s_setprio(1);
#pragma unroll
    for (int kk = 0; kk < 2; kk++)
#pragma unroll
      for (int i = 0; i < 4; i++) { MM(i, 0); MM(i, 1); }
    __builtin_amdgcn_s_setprio(0);
    __builtin_amdgcn_s_barrier();

#pragma unroll
    for (int kk = 0; kk < 2; kk++) {
#pragma unroll
      for (int i = 4; i < 8; i++) a[i][kk] = RD(Ah, wm * 128 + i * 16 + lr);
      b[2][kk] = RD(Bh, wn * 48 + 2 * 16 + lr);
    }
    if (t + 1 < NT)
      stage_unit(B + (size_t)(bn + 128) * K + k1, K, Bs[cur ^ 1] + 2 * 4096, w, l);
    __builtin_amdgcn_s_barrier();
    asm volatile("s_waitcnt lgkmcnt(0)" ::: "memory");
    __builtin_amdgcn_sched_barrier(0);
    __builtin_amdgcn_s_setprio(1);
#pragma unroll
    for (int kk = 0; kk < 2; kk++)
#pragma unroll
      for (int i = 0; i < 8; i++) MM(i, 2);
    __builtin_amdgcn_s_setprio(0);
    __builtin_amdgcn_s_barrier();

    if (t + 2 < NT) {
      stage_unit(A + (size_t)(bm) * K + k2, K, As[cur] + 0 * 4096, w, l);
      stage_unit(A + (size_t)(bm + 64) * K + k2, K, As[cur] + 1 * 4096, w, l);
    }
    __builtin_amdgcn_s_barrier();
    __builtin_amdgcn_s_setprio(1);
#pragma unroll
    for (int kk = 0; kk < 2; kk++)
#pragma unroll
      for (int i = 4; i < 8; i++) MM(i, 0);
    __builtin_amdgcn_s_setprio(0);
    __builtin_amdgcn_s_barrier();

    if (t + 2 < NT) {
      stage_unit(A + (size_t)(bm + 128) * K + k2, K, As[cur] + 2 * 4096, w, l);
      stage_unit(A + (size_t)(bm + 192) * K + k2, K, As[cur] + 3 * 4096, w, l);
      asm volatile("s_waitcnt vmcnt(4)" ::: "memory");
    } else {
      asm volatile("s_waitcnt vmcnt(0)" ::: "memory");
    }
    __builtin_amdgcn_s_barrier();
    __builtin_amdgcn_s_setprio(1);
#pragma unroll
    for (int kk = 0; kk < 2; kk++)
#pragma unroll
      for (int i = 4; i < 8; i++) MM(i, 1);
    __builtin_amdgcn_s_setprio(0);
    __builtin_amdgcn_s_barrier();
  }

#pragma unroll
  for (int i = 0; i < 8; i++)
#pragma unroll
    for (int j = 0; j < 3; j++)
#pragma unroll
      for (int r = 0; r < 4; r++) {
        int row = bm + wm * 128 + i * 16 + lg * 4 + r;
        int col = bn + wn * 48 + j * 16 + lr;
        C[(size_t)row * N + col] = f2bf(acc[i][j][r]);
      }
}

// ---------------- GEMM2: 128x256 tile, BK=64, 2-phase, TRIPLE buffer ----------------
__global__ __launch_bounds__(512, 2) void gemm_out(const u16* __restrict__ A, const u16* __restrict__ B,
                                                   float* __restrict__ C, int M, int N, int K) {
  __shared__ __align__(16) u16 As3[3 * 128 * 64];
  __shared__ __align__(16) u16 Bs3[3 * 256 * 64];
  const int tid = threadIdx.x;
  const int w = tid >> 6, l = tid & 63;
  const int lr = l & 15, lg = l >> 4;
  const int wm = w >> 2, wn = w & 3;
  const int xsw = lr & 7;
  const int bm = blockIdx.y * 128, bn = blockIdx.x * 256;
  const int NT = K >> 6;

  f32x4 acc[4][4] = {};
  s16x8 a[4][2], b[4][2];

#pragma unroll
  for (int u = 0; u < 2; u++) stage_unit(A + (size_t)(bm + 64 * u) * K, K, As3 + u * 4096, w, l);
#pragma unroll
  for (int u = 0; u < 4; u++) stage_unit(B + (size_t)(bn + 64 * u) * K, K, Bs3 + u * 4096, w, l);
#pragma unroll
  for (int u = 0; u < 2; u++) stage_unit(A + (size_t)(bm + 64 * u) * K + 64, K, As3 + 8192 + u * 4096, w, l);
#pragma unroll
  for (int u = 0; u < 4; u++) stage_unit(B + (size_t)(bn + 64 * u) * K + 64, K, Bs3 + 16384 + u * 4096, w, l);
  asm volatile("s_waitcnt vmcnt(6)" ::: "memory");
  __builtin_amdgcn_s_barrier();

  int cur = 0;
  for (int t = 0; t < NT; t++) {
    const u16* Ah = As3 + cur * 8192;
    const u16* Bh = Bs3 + cur * 16384;
    int sb = cur + 2; if (sb >= 3) sb -= 3;
    u16* Asb = As3 + sb * 8192;
    u16* Bsb = Bs3 + sb * 16384;
    const int k2 = (t + 2) * 64;

#pragma unroll
    for (int kk = 0; kk < 2; kk++) {
#pragma unroll
      for (int i = 0; i < 4; i++) a[i][kk] = RD(Ah, wm * 64 + i * 16 + lr);
#pragma unroll
      for (int j = 0; j < 2; j++) b[j][kk] = RD(Bh, wn * 64 + j * 16 + lr);
    }
    if (t + 2 < NT) {
      stage_unit(B + (size_t)(bn) * K + k2, K, Bsb + 0 * 4096, w, l);
      stage_unit(B + (size_t)(bn + 64) * K + k2, K, Bsb + 1 * 4096, w, l);
      stage_unit(B + (size_t)(bn + 128) * K + k2, K, Bsb + 2 * 4096, w, l);
    }
    __builtin_amdgcn_s_barrier();
    asm volatile("s_waitcnt lgkmcnt(0)" ::: "memory");
    __builtin_amdgcn_sched_barrier(0);
    __builtin_amdgcn_s_setprio(1);
#pragma unroll
    for (int kk = 0; kk < 2; kk++)
#pragma unroll
      for (int i = 0; i < 4; i++) { MM(i, 0); MM(i, 1); }
    __builtin_amdgcn_s_setprio(0);
    __builtin_amdgcn_s_barrier();

#pragma unroll
    for (int kk = 0; kk < 2; kk++)
#pragma unroll
      for (int j = 2; j < 4; j++) b[j][kk] = RD(Bh, wn * 64 + j * 16 + lr);
    if (t + 2 < NT) {
      stage_unit(B + (size_t)(bn + 192) * K + k2, K, Bsb + 3 * 4096, w, l);
      stage_unit(A + (size_t)(bm) * K + k2, K, Asb + 0 * 4096, w, l);
      stage_unit(A + (size_t)(bm + 64) * K + k2, K, Asb + 1 * 4096, w, l);
      asm volatile("s_waitcnt vmcnt(6)" ::: "memory");
    } else {
      asm volatile("s_waitcnt vmcnt(0)" ::: "memory");
    }
    __builtin_amdgcn_s_barrier();
    asm volatile("s_waitcnt lgkmcnt(0)" ::: "memory");
    __builtin_amdgcn_sched_barrier(0);
    __builtin_amdgcn_s_setprio(1);
#pragma unroll
    for (int kk = 0; kk < 2; kk++)
#pragma unroll
      for (int i = 0; i < 4; i++) { MM(i, 2); MM(i, 3); }
    __builtin_amdgcn_s_setprio(0);
    __builtin_amdgcn_s_barrier();

    cur = (cur == 2) ? 0 : cur + 1;
  }

#pragma unroll
  for (int i = 0; i < 4; i++)
#pragma unroll
    for (int j = 0; j < 4; j++)
#pragma unroll
      for (int r = 0; r < 4; r++) {
        int row = bm + wm * 64 + i * 16 + lg * 4 + r;
        int col = bn + wn * 64 + j * 16 + lr;
        C[(size_t)row * N + col] = acc[i][j][r];
      }
}
#undef RD
#undef MM

// ---------------- flash attention: 8 waves, 32 q-rows/wave, 32x32x16 MFMA ----------------
// Block x handles qtiles (15-x) [waves 0-3] and x [waves 4-7] over a shared KV prefix:
// uniform 34 tile-computations per block. K,V double-buffered in LDS, XOR-swizzled.
__device__ inline void stage_kv8(const u16* __restrict__ qkv, const u16* __restrict__ Vt,
                                 char* Kb, char* Vb, int kv0, int hkv, int w, int l) {
  const int c16 = l & 15, r16 = l >> 4;
  const int c8 = l & 7, r8 = l >> 3;
#pragma unroll
  for (int i = 0; i < 2; i++) {
    int row = i * 32 + w * 4 + r16;
    const char* src = (const char*)(qkv + (size_t)(kv0 + row) * QKVD + KOFF + hkv * HD) +
                      ((c16 ^ (row & 7)) << 4);
    gl_lds16(src, Kb + i * 8192 + w * 1024);
  }
#pragma unroll
  for (int i = 0; i < 2; i++) {
    int drow = i * 64 + w * 8 + r8;
    const char* src = (const char*)(Vt + (size_t)(hkv * HD + drow) * T_SEQ + kv0) +
                      ((c8 ^ (drow & 7)) << 4);
    gl_lds16(src, Vb + i * 8192 + w * 1024);
  }
}

__global__ __launch_bounds__(512, 2) void attn_fwd(const u16* __restrict__ qkv, const u16* __restrict__ Vt,
                                                   u16* __restrict__ attnout) {
  __shared__ __align__(16) char Ks[2][64 * 256];
  __shared__ __align__(16) char Vs[2][128 * 128];
  const int tid = threadIdx.x;
  const int w = tid >> 6, l = tid & 63;
  const int l31 = l & 31, hi = l >> 5, l7 = l & 7;
  const int h = blockIdx.y, hkv = h >> 2;
  const int x = blockIdx.x;
  const int qt = (w < 4) ? (15 - x) : x;
  const int q0 = qt * 128 + (w & 3) * 32;
  const int my_nt = 2 * qt + 2;
  const int NT = 32 - 2 * x;
  const int q_abs = q0 + l31;
  const float scale = 0.08838834764831845f;

  s16x8 qf[8];
  const u16* qb = qkv + (size_t)q_abs * QKVD + h * HD + hi * 8;
#pragma unroll
  for (int dk = 0; dk < 8; dk++) qf[dk] = *(const s16x8*)(qb + dk * 16);

  f32x16 acc[4] = {};
  float m_run = -1e30f, l_run = 0.0f;

  stage_kv8(qkv, Vt, Ks[0], Vs[0], 0, hkv, w, l);
  asm volatile("s_waitcnt vmcnt(0)" ::: "memory");
  __syncthreads();
  int cur = 0;
  for (int kt = 0; kt < NT; kt++) {
    if (kt + 1 < NT)
      stage_kv8(qkv, Vt, Ks[cur ^ 1], Vs[cur ^ 1], (kt + 1) * 64, hkv, w, l);
    if (kt < my_nt) {
      // QK^T swapped: S[kv][q], lane owns q-col l31, 16 kv rows per 32-tile
      const char* kb = Ks[cur];
      f32x16 s0 = {}, s1 = {};
#pragma unroll
      for (int dk = 0; dk < 8; dk++) {
        int cs = (((dk << 1) + hi) ^ l7) << 4;
        s16x8 k0 = *(const s16x8*)(kb + l31 * 256 + cs);
        s16x8 k1 = *(const s16x8*)(kb + (32 + l31) * 256 + cs);
        s0 = __builtin_amdgcn_mfma_f32_32x32x16_bf16(k0, qf[dk], s0, 0, 0, 0);
        s1 = __builtin_amdgcn_mfma_f32_32x32x16_bf16(k1, qf[dk], s1, 0, 0, 0);
      }
      const bool masked = (kt >= my_nt - 2);
      float ps[32];
      float pmax = -1e30f;
#pragma unroll
      for (int r = 0; r < 16; r++) {
        float v0 = s0[r] * scale, v1 = s1[r] * scale;
        if (masked) {
          int kvo = kt * 64 + (r & 3) + 8 * (r >> 2) + 4 * hi;
          if (kvo > q_abs) v0 = -1e30f;
          if (kvo + 32 > q_abs) v1 = -1e30f;
        }
        ps[r] = v0; ps[16 + r] = v1;
        pmax = fmaxf(pmax, fmaxf(v0, v1));
      }
      pmax = fmaxf(pmax, __shfl_xor(pmax, 32, 64));
      // defer-max (T13): rescale only when max grew by > 8
      if (!__all(pmax <= m_run + 8.0f)) {
        float m_new = fmaxf(m_run, pmax);
        float fac = __expf(m_run - m_new);
        l_run *= fac;
#pragma unroll
        for (int r = 0; r < 16; r++) {
          float fr = __shfl(fac, (r & 3) + 8 * (r >> 2) + 4 * hi, 64);
#pragma unroll
          for (int db = 0; db < 4; db++) acc[db][r] *= fr;
        }
        m_run = m_new;
      }
      float psum = 0.f;
#pragma unroll
      for (int i = 0; i < 32; i++) { float e = __expf(ps[i] - m_run); ps[i] = e; psum += e; }
      psum += __shfl_xor(psum, 32, 64);
      l_run += psum;
      // P -> bf16 A-fragments: pure in-lane packing (kv order matches permuted Vt)
      s16x8 pf[4];
#pragma unroll
      for (int ks = 0; ks < 4; ks++) {
        union { u32 uw[4]; s16x8 v; } u;
#pragma unroll
        for (int q = 0; q < 4; q++) u.uw[q] = cvtpk_bf16(ps[8 * ks + 2 * q], ps[8 * ks + 2 * q + 1]);
        pf[ks] = u.v;
      }
      const char* vb = Vs[cur];
#pragma unroll
      for (int db = 0; db < 4; db++)
#pragma unroll
        for (int ks = 0; ks < 4; ks++) {
          s16x8 vf = *(const s16x8*)(vb + (db * 32 + l31) * 128 + ((((ks << 1) + hi) ^ l7) << 4));
          acc[db] = __builtin_amdgcn_mfma_f32_32x32x16_bf16(pf[ks], vf, acc[db], 0, 0, 0);
        }
    }
    asm volatile("s_waitcnt vmcnt(0)" ::: "memory");
    __syncthreads();
    cur ^= 1;
  }
#pragma unroll
  for (int r = 0; r < 16; r++) {
    int cr = (r & 3) + 8 * (r >> 2) + 4 * hi;
    float ln = __shfl(l_run, cr, 64);
    float inv = 1.0f / ln;
    u16* ob = attnout + (size_t)(q0 + cr) * HID + h * HD + l31;
#pragma unroll
    for (int db = 0; db < 4; db++) ob[db * 32] = f2bf(acc[db][r] * inv);
  }
}

extern "C" void kernel_launch(void* const* d_in, const int* in_sizes, int n_in,
                              void* d_out, int out_size, void* d_ws, size_t ws_size,
                              hipStream_t stream) {
  const int*   positions = (const int*)d_in[0];
  const float* X         = (const float*)d_in[1];
  const float* Wqkv      = (const float*)d_in[2];
  const float* Wo        = (const float*)d_in[3];
  float* out = (float*)d_out;

  char* ws = (char*)d_ws;
  size_t off = 0;
  u16* Xbf    = (u16*)(ws + off); off += (size_t)T_SEQ * HID * 2;
  u16* Wqkvt  = (u16*)(ws + off); off += (size_t)QKVD * HID * 2;
  u16* Wot    = (u16*)(ws + off); off += (size_t)HID * HID * 2;
  u16* qkv    = (u16*)(ws + off); off += (size_t)T_SEQ * QKVD * 2;
  u16* Vt     = (u16*)(ws + off); off += (size_t)NKV * HD * T_SEQ * 2;
  u16* attnb  = (u16*)(ws + off); off += (size_t)T_SEQ * HID * 2;

  cast_f32_bf16<<<dim3((T_SEQ * HID) / (256 * 4)), dim3(256), 0, stream>>>(X, Xbf, T_SEQ * HID);
  transpose_cast<<<dim3(QKVD / 32, HID / 32), dim3(32, 8), 0, stream>>>(Wqkv, Wqkvt, HID, QKVD);
  transpose_cast<<<dim3(HID / 32, HID / 32), dim3(32, 8), 0, stream>>>(Wo, Wot, HID, HID);
  gemm_qkv<<<dim3(QKVD / 192, T_SEQ / 256), dim3(512), 0, stream>>>(Xbf, Wqkvt, qkv, T_SEQ, QKVD, HID);
  rope_kernel<<<dim3(T_SEQ, 10), dim3(256), 0, stream>>>(qkv, positions);
  vtrans<<<dim3(T_SEQ / 32, HD / 32, NKV), dim3(32, 8), 0, stream>>>(qkv, Vt);
  attn_fwd<<<dim3(8, 32), dim3(512), 0, stream>>>(qkv, Vt, attnb);
  gemm_out<<<dim3(HID / 256, T_SEQ / 128), dim3(512), 0, stream>>>(attnb, Wot, out, T_SEQ, HID, HID);
}